// Round 1
// baseline (110.627 us; speedup 1.0000x reference)
//
#include <hip/hip_runtime.h>

#define SEQ 79
#define DM 1024
#define BATCHN 512
#define NROWS (BATCHN * SEQ)        // 40448
#define ROWSTRIDE 68                // floats per ws row: u'[32], v'[32], color, pad(3)
#define NPAIR (BATCHN * SEQ * SEQ)  // 3,195,392

// ---------------- K1: per-(b,n) row -> u'[32], v'[32], color -------------
// One wave (64 lanes) per row. Lane l handles x elements c = q*256 + l*4 + t
// (q=0..3, t=0..3) via coalesced float4 loads. Projection weights preloaded
// into VGPRs once (reused across grid-stride rows). Butterfly reduce the 7
// dot products, then lanes 0..31 compute u'_k, lanes 32..63 compute v'_k.
__global__ __launch_bounds__(256) void k1_embed(
    const float* __restrict__ x,
    const float* __restrict__ piece_w, const float* __restrict__ piece_b,
    const float* __restrict__ color_w, const float* __restrict__ color_b,
    const float* __restrict__ mlp1_w,  const float* __restrict__ mlp1_b,
    float* __restrict__ ws)
{
    const int lane = threadIdx.x & 63;
    const int wid  = (blockIdx.x * blockDim.x + threadIdx.x) >> 6;
    const int nw   = (gridDim.x * blockDim.x) >> 6;
    const int k    = lane & 31;

    // per-lane projection weights: c = q*256 + lane*4 + t, 7 outputs each
    float wp[4][4][7];
#pragma unroll
    for (int q = 0; q < 4; ++q)
#pragma unroll
        for (int t = 0; t < 4; ++t) {
            const int c = q * 256 + lane * 4 + t;
#pragma unroll
            for (int e = 0; e < 6; ++e) wp[q][t][e] = piece_w[c * 6 + e];
            wp[q][t][6] = color_w[c];
        }

    // per-lane u'/v' weights (lane<32 -> u'_k, lane>=32 -> v'_k)
    const bool is_u = (lane < 32);
    float wsp0 = mlp1_w[0 * 32 + k];
    float wsp1 = mlp1_w[1 * 32 + k];
    if (!is_u) { wsp0 = -wsp0; wsp1 = -wsp1; }
    const float bias = is_u ? mlp1_b[k] : 0.0f;
    float wc[6];
#pragma unroll
    for (int c = 0; c < 6; ++c)
        wc[c] = mlp1_w[((is_u ? 2 : 8) + c) * 32 + k];

    float pb[6];
#pragma unroll
    for (int e = 0; e < 6; ++e) pb[e] = piece_b[e];
    const float cb = color_b[0];

    for (int row = wid; row < NROWS; row += nw) {
        const float4* xr = (const float4*)(x + (size_t)row * DM);
        float4 xv[4];
#pragma unroll
        for (int q = 0; q < 4; ++q) xv[q] = xr[q * 64 + lane];

        float acc[7] = {0.f, 0.f, 0.f, 0.f, 0.f, 0.f, 0.f};
#pragma unroll
        for (int q = 0; q < 4; ++q) {
            const float xs[4] = {xv[q].x, xv[q].y, xv[q].z, xv[q].w};
#pragma unroll
            for (int t = 0; t < 4; ++t)
#pragma unroll
                for (int e = 0; e < 7; ++e)
                    acc[e] = fmaf(xs[t], wp[q][t][e], acc[e]);
        }

        // full-wave butterfly reduce: all lanes end with the row sums
#pragma unroll
        for (int e = 0; e < 7; ++e) {
#pragma unroll
            for (int m = 32; m >= 1; m >>= 1)
                acc[e] += __shfl_xor(acc[e], m, 64);
        }

        float p[6];
#pragma unroll
        for (int e = 0; e < 6; ++e) p[e] = acc[e] + pb[e];
        const float col = acc[6] + cb;

        const int n = row % SEQ;                 // token index
        const float fx = (n < 64) ? (float)(n >> 3) : 0.0f;
        const float fy = (n < 64) ? (float)(n & 7) : 0.0f;

        float val = bias;
        val = fmaf(fx, wsp0, val);
        val = fmaf(fy, wsp1, val);
#pragma unroll
        for (int c = 0; c < 6; ++c) val = fmaf(p[c], wc[c], val);

        float* wr = ws + (size_t)row * ROWSTRIDE;
        wr[lane] = val;
        if (lane == 0) wr[64] = col;
    }
}

// ---------------- K2: per-(b,i,j) pair MLP ------------------------------
__device__ __forceinline__ float gelu_tanh(float a) {
    // 0.5*a*(1 + tanh(0.79788456*(a + 0.044715*a^3)))
    const float x2 = a * a;
    float t = a * 0.7978845608028654f;
    t = t * fmaf(0.044715f, x2, 1.0f);
    const float e = __expf(t + t);
    const float r = __builtin_amdgcn_rcpf(e + 1.0f);
    const float th = fmaf(-2.0f, r, 1.0f);   // tanh(t) = 1 - 2/(e^{2t}+1)
    const float ah = 0.5f * a;
    return fmaf(ah, th, ah);
}

__global__ __launch_bounds__(256) void k2_pair(
    const float* __restrict__ ws,
    const float* __restrict__ mlp1_w,
    const float* __restrict__ mlp2_w, const float* __restrict__ mlp2_b,
    float* __restrict__ out)
{
    const unsigned p = blockIdx.x * 256u + threadIdx.x;
    if (p >= (unsigned)NPAIR) return;
    const unsigned b = p / (SEQ * SEQ);
    const unsigned r = p - b * (SEQ * SEQ);
    const unsigned i = r / SEQ;
    const unsigned j = r - i * SEQ;

    const float* ui = ws + (size_t)(b * SEQ + i) * ROWSTRIDE;
    const float* vj = ws + (size_t)(b * SEQ + j) * ROWSTRIDE;

    float u[32], v[32];
#pragma unroll
    for (int q = 0; q < 8; ++q) {
        const float4 t4 = ((const float4*)ui)[q];
        u[4 * q + 0] = t4.x; u[4 * q + 1] = t4.y;
        u[4 * q + 2] = t4.z; u[4 * q + 3] = t4.w;
    }
#pragma unroll
    for (int q = 0; q < 8; ++q) {
        const float4 t4 = ((const float4*)(vj + 32))[q];
        v[4 * q + 0] = t4.x; v[4 * q + 1] = t4.y;
        v[4 * q + 2] = t4.z; v[4 * q + 3] = t4.w;
    }
    const float same = (ui[64] == vj[64]) ? 1.0f : 0.0f;

    float acc[8] = {0.f, 0.f, 0.f, 0.f, 0.f, 0.f, 0.f, 0.f};
#pragma unroll
    for (int k = 0; k < 32; ++k) {
        float a = u[k] + v[k];
        a = fmaf(same, mlp1_w[14 * 32 + k], a);   // uniform -> scalar load
        const float h = gelu_tanh(a);
#pragma unroll
        for (int e = 0; e < 8; ++e)
            acc[e] = fmaf(h, mlp2_w[k * 8 + e], acc[e]);
    }

    const size_t ob = (size_t)b * (8 * SEQ * SEQ) + (size_t)i * SEQ + j;
#pragma unroll
    for (int e = 0; e < 8; ++e)
        out[ob + (size_t)e * (SEQ * SEQ)] = acc[e] + mlp2_b[e];
}

extern "C" void kernel_launch(void* const* d_in, const int* in_sizes, int n_in,
                              void* d_out, int out_size, void* d_ws, size_t ws_size,
                              hipStream_t stream) {
    const float* x       = (const float*)d_in[0];
    const float* piece_w = (const float*)d_in[1];
    const float* piece_b = (const float*)d_in[2];
    const float* color_w = (const float*)d_in[3];
    const float* color_b = (const float*)d_in[4];
    const float* mlp1_w  = (const float*)d_in[5];
    const float* mlp1_b  = (const float*)d_in[6];
    const float* mlp2_w  = (const float*)d_in[7];
    const float* mlp2_b  = (const float*)d_in[8];
    float* out = (float*)d_out;
    float* ws  = (float*)d_ws;   // needs NROWS*ROWSTRIDE*4 = ~11 MB

    hipLaunchKernelGGL(k1_embed, dim3(1024), dim3(256), 0, stream,
                       x, piece_w, piece_b, color_w, color_b, mlp1_w, mlp1_b, ws);
    hipLaunchKernelGGL(k2_pair, dim3(NPAIR / 256), dim3(256), 0, stream,
                       ws, mlp1_w, mlp2_w, mlp2_b, out);
}